// Round 1
// baseline (503.256 us; speedup 1.0000x reference)
//
#include <hip/hip_runtime.h>

#define B_   2
#define S_   2048
#define HID_ 1280
#define H_   20
#define D_   64
#define BH_  (B_*H_)   // 40
#define M_   (B_*S_)   // 4096

typedef __bf16 bf16x8 __attribute__((ext_vector_type(8)));
typedef float  f32x4  __attribute__((ext_vector_type(4)));
typedef unsigned short u16x8 __attribute__((ext_vector_type(8)));
typedef unsigned short u16x4 __attribute__((ext_vector_type(4)));

__device__ __forceinline__ unsigned short f2bf(float x){
  union { float f; unsigned int u; } v; v.f = x;
  unsigned int u = v.u;
  u += 0x7fffu + ((u >> 16) & 1u);   // round-to-nearest-even
  return (unsigned short)(u >> 16);
}

// ---------------- RoPE tables: cos/sin [S][32] ----------------
__global__ void rope_tables(float* __restrict__ cosT, float* __restrict__ sinT){
  int idx = blockIdx.x * 256 + threadIdx.x;   // 0 .. 2048*32-1
  int s = idx >> 5, j = idx & 31;
  float inv = 1.0f / powf(10000.0f, (float)(2*j) / 64.0f);
  float ang = (float)s * inv;
  float sn, cs;
  sincosf(ang, &sn, &cs);
  cosT[idx] = cs; sinT[idx] = sn;
}

// ---------------- QKV projection GEMM + bias + (scale) + RoPE epilogue ----------------
// C[m][n] = sum_k hs[m][k] * W[k][n];  z=0:Q (scale+rope), z=1:K (rope), z=2:V
__global__ __launch_bounds__(256) void qkv_gemm(
    const float* __restrict__ hs,
    const float* __restrict__ Wq, const float* __restrict__ bq,
    const float* __restrict__ Wk, const float* __restrict__ bk,
    const float* __restrict__ Wv, const float* __restrict__ bv,
    const float* __restrict__ cosT, const float* __restrict__ sinT,
    unsigned short* __restrict__ Qb, unsigned short* __restrict__ Kb,
    unsigned short* __restrict__ Vb)
{
  const int mode = blockIdx.z;
  const float* W    = (mode==0) ? Wq : (mode==1 ? Wk : Wv);
  const float* bias = (mode==0) ? bq : (mode==1 ? bk : bv);
  unsigned short* dst = (mode==0) ? Qb : (mode==1 ? Kb : Vb);

  const int n0 = blockIdx.x * 128;
  const int m0 = blockIdx.y * 128;
  const int tid  = threadIdx.x;
  const int lane = tid & 63, wave = tid >> 6;
  const int c = lane & 15, quad = lane >> 4;
  const int wm = (wave & 1) * 64, wn = (wave >> 1) * 64;

  // pitch 40 shorts = 80 B: 16B-aligned rows, 2-way (free) bank aliasing
  __shared__ __align__(16) unsigned short As[128][40];
  __shared__ __align__(16) unsigned short Bs[128][40];

  f32x4 acc[4][4] = {};

  for (int k0 = 0; k0 < HID_; k0 += 32){
    __syncthreads();
    // stage A tile: hs[m0..+128][k0..+32], fp32 -> bf16
    #pragma unroll
    for (int p = 0; p < 4; ++p){
      int chunk = tid + p*256;            // 0..1023
      int row = chunk >> 3, c4 = (chunk & 7) * 4;
      const float4 f = *(const float4*)(hs + (size_t)(m0+row)*HID_ + k0 + c4);
      u16x4 o; o.x = f2bf(f.x); o.y = f2bf(f.y); o.z = f2bf(f.z); o.w = f2bf(f.w);
      *(u16x4*)&As[row][c4] = o;
    }
    // stage B tile transposed: Bs[n][k] = W[k0+k][n0+n]
    #pragma unroll
    for (int p = 0; p < 4; ++p){
      int chunk = tid + p*256;            // 0..1023
      int k = chunk >> 5, n4 = (chunk & 31) * 4;
      const float4 f = *(const float4*)(W + (size_t)(k0+k)*HID_ + n0 + n4);
      Bs[n4+0][k] = f2bf(f.x);
      Bs[n4+1][k] = f2bf(f.y);
      Bs[n4+2][k] = f2bf(f.z);
      Bs[n4+3][k] = f2bf(f.w);
    }
    __syncthreads();

    bf16x8 af[4], bfr[4];
    #pragma unroll
    for (int mi=0; mi<4; ++mi) af[mi]  = *(const bf16x8*)&As[wm + mi*16 + c][quad*8];
    #pragma unroll
    for (int ni=0; ni<4; ++ni) bfr[ni] = *(const bf16x8*)&Bs[wn + ni*16 + c][quad*8];
    #pragma unroll
    for (int mi=0; mi<4; ++mi)
      #pragma unroll
      for (int ni=0; ni<4; ++ni)
        acc[mi][ni] = __builtin_amdgcn_mfma_f32_16x16x32_bf16(af[mi], bfr[ni], acc[mi][ni], 0,0,0);
  }

  // epilogue: wave's 64 cols == exactly one head
  const int h = (n0 + wn) >> 6;
  #pragma unroll
  for (int mi=0; mi<4; ++mi){
    #pragma unroll
    for (int i=0;i<4;++i){
      int row = m0 + wm + mi*16 + quad*4 + i;
      int b = row >> 11, s = row & (S_-1);
      size_t obase = ((size_t)(b*H_ + h)*S_ + s)*D_;
      if (mode < 2){
        #pragma unroll
        for (int ni=0; ni<2; ++ni){
          int d1 = ni*16 + c;             // 0..31
          float x1 = acc[mi][ni  ][i] + bias[n0 + wn + d1];
          float x2 = acc[mi][ni+2][i] + bias[n0 + wn + d1 + 32];
          if (mode == 0){ x1 *= 0.125f; x2 *= 0.125f; }   // D^-0.5, before rope
          float cs = cosT[s*32 + d1], sn = sinT[s*32 + d1];
          dst[obase + d1]      = f2bf(x1*cs - x2*sn);
          dst[obase + d1 + 32] = f2bf(x2*cs + x1*sn);
        }
      } else {
        #pragma unroll
        for (int ni=0; ni<4; ++ni){
          int d = ni*16 + c;
          dst[obase + d] = f2bf(acc[mi][ni][i] + bias[n0 + wn + d]);
        }
      }
    }
  }
}

// ---------------- Flash attention: 64 q-rows / block, K/V tiles of 64 ----------------
__global__ __launch_bounds__(256) void attn(
    const unsigned short* __restrict__ Qb,
    const unsigned short* __restrict__ Kb,
    const unsigned short* __restrict__ Vb,
    const float* __restrict__ mask,
    float* __restrict__ out)
{
  const int tid  = threadIdx.x;
  const int lane = tid & 63, wave = tid >> 6;
  const int c = lane & 15, quad = lane >> 4;
  const int bh = blockIdx.y, b = bh / H_, h = bh % H_;
  const size_t base = (size_t)bh * (S_ * D_);
  const int q0 = blockIdx.x * 64;

  __shared__ __align__(16) unsigned short Ks[64][72];      // [key][d]
  __shared__ __align__(16) unsigned short Vs[64][72];      // [d][key] (transposed)
  __shared__ __align__(16) unsigned short Ps[4][16][72];   // per-wave P: [q][key]
  __shared__ float mask_s[64];

  // Q fragments (A-operand): lane&15 = q-row, quad*8+j = d
  const int qrow = q0 + wave*16 + c;
  const bf16x8 aq0 = *(const bf16x8*)(Qb + base + (size_t)qrow*D_ + quad*8);
  const bf16x8 aq1 = *(const bf16x8*)(Qb + base + (size_t)qrow*D_ + quad*8 + 32);

  float m_i[4], l_i[4];
  f32x4 O[4] = {};
  #pragma unroll
  for (int i=0;i<4;++i){ m_i[i] = -1e30f; l_i[i] = 0.f; }

  for (int kt0 = 0; kt0 < S_; kt0 += 64){
    __syncthreads();
    // stage K [key][d]
    #pragma unroll
    for (int p=0;p<2;++p){
      int chunk = tid + p*256;
      int r = chunk >> 3, c8 = (chunk & 7)*8;
      *(u16x8*)&Ks[r][c8] = *(const u16x8*)(Kb + base + (size_t)(kt0+r)*D_ + c8);
    }
    // stage V transposed -> Vs[d][key]
    #pragma unroll
    for (int p=0;p<2;++p){
      int chunk = tid + p*256;
      int r = chunk >> 3, d0 = (chunk & 7)*8;
      u16x8 v = *(const u16x8*)(Vb + base + (size_t)(kt0+r)*D_ + d0);
      #pragma unroll
      for (int j=0;j<8;++j) Vs[d0+j][r] = v[j];
    }
    if (tid < 64) mask_s[tid] = mask[b*S_ + kt0 + tid];
    __syncthreads();

    // scores st[kt] = Q · K^T + mask   (C-layout: col=key=lane&15, row=quad*4+i)
    f32x4 st[4];
    #pragma unroll
    for (int kt=0;kt<4;++kt){
      bf16x8 bk0 = *(const bf16x8*)&Ks[kt*16 + c][quad*8];
      bf16x8 bk1 = *(const bf16x8*)&Ks[kt*16 + c][quad*8 + 32];
      f32x4 z = {0.f,0.f,0.f,0.f};
      z = __builtin_amdgcn_mfma_f32_16x16x32_bf16(aq0, bk0, z, 0,0,0);
      z = __builtin_amdgcn_mfma_f32_16x16x32_bf16(aq1, bk1, z, 0,0,0);
      float mk = mask_s[kt*16 + c];
      #pragma unroll
      for (int i=0;i<4;++i) z[i] += mk;
      st[kt] = z;
    }

    // online softmax: rows of quad live in its 16 lanes
    float mnew[4], alpha[4];
    #pragma unroll
    for (int i=0;i<4;++i){
      float mx = fmaxf(fmaxf(st[0][i], st[1][i]), fmaxf(st[2][i], st[3][i]));
      #pragma unroll
      for (int off=8; off>=1; off>>=1) mx = fmaxf(mx, __shfl_xor(mx, off, 64));
      mnew[i] = fmaxf(m_i[i], mx);
      alpha[i] = __expf(m_i[i] - mnew[i]);
    }
    #pragma unroll
    for (int kt=0;kt<4;++kt)
      #pragma unroll
      for (int i=0;i<4;++i)
        st[kt][i] = __expf(st[kt][i] - mnew[i]);
    #pragma unroll
    for (int i=0;i<4;++i){
      float sm = st[0][i]+st[1][i]+st[2][i]+st[3][i];
      #pragma unroll
      for (int off=8; off>=1; off>>=1) sm += __shfl_xor(sm, off, 64);
      l_i[i] = l_i[i]*alpha[i] + sm;
      m_i[i] = mnew[i];
    }
    #pragma unroll
    for (int dt=0;dt<4;++dt)
      #pragma unroll
      for (int i=0;i<4;++i)
        O[dt][i] *= alpha[i];

    // P: C-layout -> LDS -> A-layout
    #pragma unroll
    for (int kt=0;kt<4;++kt)
      #pragma unroll
      for (int i=0;i<4;++i)
        Ps[wave][quad*4+i][kt*16+c] = f2bf(st[kt][i]);
    __syncthreads();

    bf16x8 ap0 = *(const bf16x8*)&Ps[wave][c][quad*8];
    bf16x8 ap1 = *(const bf16x8*)&Ps[wave][c][quad*8 + 32];
    #pragma unroll
    for (int dt=0;dt<4;++dt){
      bf16x8 bv0 = *(const bf16x8*)&Vs[dt*16 + c][quad*8];
      bf16x8 bv1 = *(const bf16x8*)&Vs[dt*16 + c][quad*8 + 32];
      O[dt] = __builtin_amdgcn_mfma_f32_16x16x32_bf16(ap0, bv0, O[dt], 0,0,0);
      O[dt] = __builtin_amdgcn_mfma_f32_16x16x32_bf16(ap1, bv1, O[dt], 0,0,0);
    }
  }

  #pragma unroll
  for (int dt=0;dt<4;++dt)
    #pragma unroll
    for (int i=0;i<4;++i){
      int s = q0 + wave*16 + quad*4 + i;
      out[((size_t)b*S_ + s)*HID_ + h*D_ + dt*16 + c] = O[dt][i] / l_i[i];
    }
}

extern "C" void kernel_launch(void* const* d_in, const int* in_sizes, int n_in,
                              void* d_out, int out_size, void* d_ws, size_t ws_size,
                              hipStream_t stream){
  const float* hs   = (const float*)d_in[0];
  const float* mask = (const float*)d_in[1];
  const float* Wq   = (const float*)d_in[2];
  const float* bq   = (const float*)d_in[3];
  const float* Wk   = (const float*)d_in[4];
  const float* bk   = (const float*)d_in[5];
  const float* Wv   = (const float*)d_in[6];
  const float* bv   = (const float*)d_in[7];
  float* out = (float*)d_out;

  float* cosT = (float*)d_ws;
  float* sinT = cosT + S_*32;
  unsigned short* Qb = (unsigned short*)(sinT + S_*32);
  unsigned short* Kb = Qb + (size_t)BH_*S_*D_;
  unsigned short* Vb = Kb + (size_t)BH_*S_*D_;

  hipLaunchKernelGGL(rope_tables, dim3(S_*32/256), dim3(256), 0, stream, cosT, sinT);
  hipLaunchKernelGGL(qkv_gemm, dim3(HID_/128, M_/128, 3), dim3(256), 0, stream,
                     hs, Wq, bq, Wk, bk, Wv, bv, cosT, sinT, Qb, Kb, Vb);
  hipLaunchKernelGGL(attn, dim3(S_/64, BH_), dim3(256), 0, stream, Qb, Kb, Vb, mask, out);
}

// Round 2
// 356.210 us; speedup vs baseline: 1.4128x; 1.4128x over previous
//
#include <hip/hip_runtime.h>

#define B_   2
#define S_   2048
#define HID_ 1280
#define H_   20
#define D_   64
#define BH_  (B_*H_)   // 40
#define M_   (B_*S_)   // 4096

typedef __bf16 bf16x8 __attribute__((ext_vector_type(8)));
typedef float  f32x4  __attribute__((ext_vector_type(4)));
typedef unsigned short u16x8 __attribute__((ext_vector_type(8)));
typedef unsigned short u16x4 __attribute__((ext_vector_type(4)));

__device__ __forceinline__ unsigned short f2bf(float x){
  union { float f; unsigned int u; } v; v.f = x;
  unsigned int u = v.u;
  u += 0x7fffu + ((u >> 16) & 1u);   // round-to-nearest-even
  return (unsigned short)(u >> 16);
}

// async 16B global -> LDS (lane i lands at lds_base + i*16)
__device__ __forceinline__ void gl_lds16(const void* g, void* lds_base_uniform){
  __builtin_amdgcn_global_load_lds(
      (const __attribute__((address_space(1))) unsigned int*)g,
      (__attribute__((address_space(3))) unsigned int*)lds_base_uniform, 16, 0, 0);
}

// ---------------- RoPE tables: cos/sin [S][32] ----------------
__global__ void rope_tables(float* __restrict__ cosT, float* __restrict__ sinT){
  int idx = blockIdx.x * 256 + threadIdx.x;
  int s = idx >> 5, j = idx & 31;
  float inv = 1.0f / powf(10000.0f, (float)(2*j) / 64.0f);
  float ang = (float)s * inv;
  float sn, cs; sincosf(ang, &sn, &cs);
  cosT[idx] = cs; sinT[idx] = sn;
}

// ---------------- hs fp32 -> bf16 ----------------
__global__ void prep_hs(const float* __restrict__ hs, unsigned short* __restrict__ hsb){
  size_t i = (size_t)(blockIdx.x * 256 + threadIdx.x) * 8;
  float4 a = *(const float4*)(hs + i), b = *(const float4*)(hs + i + 4);
  u16x8 o;
  o[0]=f2bf(a.x); o[1]=f2bf(a.y); o[2]=f2bf(a.z); o[3]=f2bf(a.w);
  o[4]=f2bf(b.x); o[5]=f2bf(b.y); o[6]=f2bf(b.z); o[7]=f2bf(b.w);
  *(u16x8*)(hsb + i) = o;
}

// ---------------- W fp32 [k][n] -> Wt bf16 [n][k] ----------------
__global__ __launch_bounds__(256) void prep_w(
    const float* __restrict__ Wq, const float* __restrict__ Wk, const float* __restrict__ Wv,
    unsigned short* __restrict__ WtAll){
  const int mode = blockIdx.z;
  const float* W = (mode==0) ? Wq : (mode==1 ? Wk : Wv);
  unsigned short* Wt = WtAll + (size_t)mode * HID_ * HID_;
  const int k0 = blockIdx.y * 64, n0 = blockIdx.x * 64;
  __shared__ __align__(16) unsigned short T[64][80];
  #pragma unroll
  for (int p = 0; p < 4; ++p){
    int idx = threadIdx.x + p*256;          // 0..1023: 64 k-rows x 16 float4
    int row = idx >> 4, c4 = (idx & 15) * 4;
    float4 f = *(const float4*)(W + (size_t)(k0+row)*HID_ + n0 + c4);
    T[c4+0][row] = f2bf(f.x); T[c4+1][row] = f2bf(f.y);
    T[c4+2][row] = f2bf(f.z); T[c4+3][row] = f2bf(f.w);
  }
  __syncthreads();
  #pragma unroll
  for (int p = 0; p < 2; ++p){
    int idx = threadIdx.x + p*256;          // 0..511: 64 n-rows x 8 chunks
    int n = idx >> 3, c8 = (idx & 7) * 8;
    u16x8 o = *(const u16x8*)&T[n][c8];
    *(u16x8*)(Wt + (size_t)(n0+n)*HID_ + k0 + c8) = o;
  }
}

// ---------------- QKV GEMM (bf16, m97-style) + bias/scale/RoPE epilogue ----------------
__global__ __launch_bounds__(256) void qkv_gemm(
    const unsigned short* __restrict__ hsb, const unsigned short* __restrict__ WtAll,
    const float* __restrict__ bq, const float* __restrict__ bk, const float* __restrict__ bv,
    const float* __restrict__ cosT, const float* __restrict__ sinT,
    unsigned short* __restrict__ Qb, unsigned short* __restrict__ Kb,
    unsigned short* __restrict__ Vb)
{
  const int mode = blockIdx.z;
  const float* bias = (mode==0) ? bq : (mode==1 ? bk : bv);
  unsigned short* dst = (mode==0) ? Qb : (mode==1 ? Kb : Vb);
  const unsigned short* Wt = WtAll + (size_t)mode * HID_ * HID_;

  const int n0 = blockIdx.x * 128;
  const int m0 = blockIdx.y * 128;
  const int tid  = threadIdx.x;
  const int lane = tid & 63, wave = tid >> 6;
  const int c = lane & 15, quad = lane >> 4;
  const int wm = (wave & 1) * 64, wn = (wave >> 1) * 64;
  const int lrow = lane >> 3, lcol = (lane & 7) * 8;   // staging map: 8 lanes/row

  __shared__ __align__(16) unsigned short As[128][64];  // [m][k], no pad (global_load_lds)
  __shared__ __align__(16) unsigned short Bs[128][64];  // [n][k]

  f32x4 acc[4][4] = {};

  for (int k0 = 0; k0 < HID_; k0 += 64){
    __syncthreads();
    #pragma unroll
    for (int j = 0; j < 4; ++j){
      int rb = j*32 + wave*8;   // this wave stages rows rb..rb+8 (1 KB)
      gl_lds16(hsb + (size_t)(m0 + rb + lrow)*HID_ + k0 + lcol, &As[rb][0]);
      gl_lds16(Wt  + (size_t)(n0 + rb + lrow)*HID_ + k0 + lcol, &Bs[rb][0]);
    }
    __syncthreads();

    #pragma unroll
    for (int kc = 0; kc < 2; ++kc){
      bf16x8 af[4], bfr[4];
      #pragma unroll
      for (int mi=0; mi<4; ++mi) af[mi]  = *(const bf16x8*)&As[wm + mi*16 + c][kc*32 + quad*8];
      #pragma unroll
      for (int ni=0; ni<4; ++ni) bfr[ni] = *(const bf16x8*)&Bs[wn + ni*16 + c][kc*32 + quad*8];
      #pragma unroll
      for (int mi=0; mi<4; ++mi)
        #pragma unroll
        for (int ni=0; ni<4; ++ni)
          acc[mi][ni] = __builtin_amdgcn_mfma_f32_16x16x32_bf16(af[mi], bfr[ni], acc[mi][ni], 0,0,0);
    }
  }

  // epilogue: wave's 64 cols == exactly one head
  const int h = (n0 + wn) >> 6;
  #pragma unroll
  for (int mi=0; mi<4; ++mi){
    #pragma unroll
    for (int i=0;i<4;++i){
      int row = m0 + wm + mi*16 + quad*4 + i;
      int b = row >> 11, s = row & (S_-1);
      size_t obase = ((size_t)(b*H_ + h)*S_ + s)*D_;
      if (mode < 2){
        #pragma unroll
        for (int ni=0; ni<2; ++ni){
          int d1 = ni*16 + c;             // 0..31
          float x1 = acc[mi][ni  ][i] + bias[n0 + wn + d1];
          float x2 = acc[mi][ni+2][i] + bias[n0 + wn + d1 + 32];
          if (mode == 0){ x1 *= 0.125f; x2 *= 0.125f; }   // D^-0.5 before rope
          float cs = cosT[s*32 + d1], sn = sinT[s*32 + d1];
          dst[obase + d1]      = f2bf(x1*cs - x2*sn);
          dst[obase + d1 + 32] = f2bf(x2*cs + x1*sn);
        }
      } else {
        #pragma unroll
        for (int ni=0; ni<4; ++ni){
          int d = ni*16 + c;
          dst[obase + d] = f2bf(acc[mi][ni][i] + bias[n0 + wn + d]);
        }
      }
    }
  }
}

// ---------------- V [b,h,s,d] -> Vt [b,h,d,s] ----------------
__global__ __launch_bounds__(256) void transpose_v(
    const unsigned short* __restrict__ Vb, unsigned short* __restrict__ Vt){
  const int bh = blockIdx.y, s0 = blockIdx.x * 64;
  const size_t base = (size_t)bh * S_ * D_;
  __shared__ __align__(16) unsigned short T[64][80];
  #pragma unroll
  for (int p = 0; p < 2; ++p){
    int idx = threadIdx.x + p*256;          // 0..511: 64 s-rows x 8 chunks
    int s = idx >> 3, c8 = (idx & 7) * 8;
    u16x8 v = *(const u16x8*)(Vb + base + (size_t)(s0+s)*D_ + c8);
    #pragma unroll
    for (int j=0;j<8;++j) T[c8+j][s] = v[j];
  }
  __syncthreads();
  #pragma unroll
  for (int p = 0; p < 2; ++p){
    int idx = threadIdx.x + p*256;          // 64 d-rows x 8 chunks
    int d = idx >> 3, s8 = (idx & 7) * 8;
    u16x8 o = *(const u16x8*)&T[d][s8];
    *(u16x8*)(Vt + base + (size_t)d*S_ + s0 + s8) = o;
  }
}

// ---------------- Flash attention, S^T formulation ----------------
// Per block: 128 q-rows, one (b,h). Waves own 32 q each. K/V tiles of 64 keys.
// S^T = K·Q^T  => C-layout: col(lane&15)=q, row(quad*4+i)=key  => softmax rows = lanes.
// O^T[d][q] accumulated via A=V^T (from Vt), B=P^T (Ps[q][key], k-contiguous).
__global__ __launch_bounds__(256) void attn(
    const unsigned short* __restrict__ Qb,
    const unsigned short* __restrict__ Kb,
    const unsigned short* __restrict__ Vt,
    const float* __restrict__ mask,
    float* __restrict__ out)
{
  const int tid  = threadIdx.x;
  const int lane = tid & 63, wave = tid >> 6;
  const int c = lane & 15, quad = lane >> 4;
  const int bh = blockIdx.y, b = bh / H_, h = bh % H_;
  const size_t base = (size_t)bh * (S_ * D_);   // same for Kb ([s][d]) and Vt ([d][s])
  const int q0 = blockIdx.x * 128;
  const int lrow = lane >> 3, lcol = (lane & 7) * 8;

  __shared__ __align__(16) unsigned short Ks[64][64];   // [key][d]  (global_load_lds)
  __shared__ __align__(16) unsigned short Vs[64][64];   // [d][key]  (global_load_lds from Vt)
  __shared__ __align__(16) unsigned short Ps[4][32][64]; // per-wave P^T as [q][key]
  __shared__ __align__(16) float mask_s[64];

  // Q as B-operand: lane c = q, k = kc*32 + quad*8 + j (contiguous from Qb rows)
  bf16x8 qf[2][2];
  #pragma unroll
  for (int qn=0; qn<2; ++qn)
    #pragma unroll
    for (int kc=0; kc<2; ++kc)
      qf[qn][kc] = *(const bf16x8*)(Qb + base + (size_t)(q0 + wave*32 + qn*16 + c)*D_ + kc*32 + quad*8);

  float m_i[2] = {-1e30f, -1e30f}, l_i[2] = {0.f, 0.f};
  f32x4 O[4][2] = {};   // [dt][qn], C-layout: col=q, row=d

  for (int kt0 = 0; kt0 < S_; kt0 += 64){
    __syncthreads();
    #pragma unroll
    for (int j = 0; j < 2; ++j){
      int rb = j*32 + wave*8;
      gl_lds16(Kb + base + (size_t)(kt0 + rb + lrow)*D_ + lcol,            &Ks[rb][0]);
      gl_lds16(Vt + base + (size_t)(rb + lrow)*S_ + kt0 + lcol,            &Vs[rb][0]);
    }
    if (tid < 64) mask_s[tid] = mask[b*S_ + kt0 + tid];
    __syncthreads();

    // S^T tile: st[kt][qn], key = kt*16 + quad*4 + i, q = qn*16 + c
    f32x4 st[4][2];
    #pragma unroll
    for (int kt=0; kt<4; ++kt){
      bf16x8 ak0 = *(const bf16x8*)&Ks[kt*16 + c][quad*8];
      bf16x8 ak1 = *(const bf16x8*)&Ks[kt*16 + c][32 + quad*8];
      float4 mk = *(const float4*)&mask_s[kt*16 + quad*4];
      #pragma unroll
      for (int qn=0; qn<2; ++qn){
        f32x4 z = {0.f,0.f,0.f,0.f};
        z = __builtin_amdgcn_mfma_f32_16x16x32_bf16(ak0, qf[qn][0], z, 0,0,0);
        z = __builtin_amdgcn_mfma_f32_16x16x32_bf16(ak1, qf[qn][1], z, 0,0,0);
        z[0] += mk.x; z[1] += mk.y; z[2] += mk.z; z[3] += mk.w;
        st[kt][qn] = z;
      }
    }

    // online softmax; row q = this lane's column
    #pragma unroll
    for (int qn=0; qn<2; ++qn){
      float mx = -1e30f;
      #pragma unroll
      for (int kt=0; kt<4; ++kt)
        #pragma unroll
        for (int i=0;i<4;++i) mx = fmaxf(mx, st[kt][qn][i]);
      mx = fmaxf(mx, __shfl_xor(mx, 16, 64));
      mx = fmaxf(mx, __shfl_xor(mx, 32, 64));
      float mnew = fmaxf(m_i[qn], mx);
      float alpha = __expf(m_i[qn] - mnew);
      float sum = 0.f;
      #pragma unroll
      for (int kt=0; kt<4; ++kt){
        #pragma unroll
        for (int i=0;i<4;++i){
          float e = __expf(st[kt][qn][i] - mnew);
          st[kt][qn][i] = e; sum += e;
        }
      }
      sum += __shfl_xor(sum, 16, 64);
      sum += __shfl_xor(sum, 32, 64);
      l_i[qn] = l_i[qn]*alpha + sum;
      m_i[qn] = mnew;
      #pragma unroll
      for (int dt=0; dt<4; ++dt){
        O[dt][qn][0]*=alpha; O[dt][qn][1]*=alpha; O[dt][qn][2]*=alpha; O[dt][qn][3]*=alpha;
      }
      // P^T -> Ps[q][key], packed 4 keys per write
      #pragma unroll
      for (int kt=0; kt<4; ++kt){
        u16x4 o; o[0]=f2bf(st[kt][qn][0]); o[1]=f2bf(st[kt][qn][1]);
                 o[2]=f2bf(st[kt][qn][2]); o[3]=f2bf(st[kt][qn][3]);
        *(u16x4*)&Ps[wave][qn*16 + c][kt*16 + quad*4] = o;
      }
    }

    // PV: O^T[d][q] += V^T[d][key] · P^T[key][q]
    bf16x8 pf[2][2];
    #pragma unroll
    for (int qn=0; qn<2; ++qn)
      #pragma unroll
      for (int k2=0; k2<2; ++k2)
        pf[qn][k2] = *(const bf16x8*)&Ps[wave][qn*16 + c][k2*32 + quad*8];
    #pragma unroll
    for (int dt=0; dt<4; ++dt){
      bf16x8 av0 = *(const bf16x8*)&Vs[dt*16 + c][quad*8];
      bf16x8 av1 = *(const bf16x8*)&Vs[dt*16 + c][32 + quad*8];
      #pragma unroll
      for (int qn=0; qn<2; ++qn){
        O[dt][qn] = __builtin_amdgcn_mfma_f32_16x16x32_bf16(av0, pf[qn][0], O[dt][qn], 0,0,0);
        O[dt][qn] = __builtin_amdgcn_mfma_f32_16x16x32_bf16(av1, pf[qn][1], O[dt][qn], 0,0,0);
      }
    }
  }

  // epilogue: lane c = q, rows = d; write float4 (4 consecutive d) per (dt,qn)
  #pragma unroll
  for (int qn=0; qn<2; ++qn){
    float inv = 1.0f / l_i[qn];
    int s = q0 + wave*32 + qn*16 + c;
    #pragma unroll
    for (int dt=0; dt<4; ++dt){
      float4 o;
      o.x = O[dt][qn][0]*inv; o.y = O[dt][qn][1]*inv;
      o.z = O[dt][qn][2]*inv; o.w = O[dt][qn][3]*inv;
      *(float4*)&out[((size_t)(b*S_ + s))*HID_ + h*D_ + dt*16 + quad*4] = o;
    }
  }
}

extern "C" void kernel_launch(void* const* d_in, const int* in_sizes, int n_in,
                              void* d_out, int out_size, void* d_ws, size_t ws_size,
                              hipStream_t stream){
  const float* hs   = (const float*)d_in[0];
  const float* mask = (const float*)d_in[1];
  const float* Wq   = (const float*)d_in[2];
  const float* bq   = (const float*)d_in[3];
  const float* Wk   = (const float*)d_in[4];
  const float* bk   = (const float*)d_in[5];
  const float* Wv   = (const float*)d_in[6];
  const float* bv   = (const float*)d_in[7];
  float* out = (float*)d_out;

  float* cosT = (float*)d_ws;
  float* sinT = cosT + S_*32;
  unsigned short* hsb   = (unsigned short*)(sinT + S_*32);
  unsigned short* WtAll = hsb + (size_t)M_*HID_;
  unsigned short* Qb = WtAll + (size_t)3*HID_*HID_;
  unsigned short* Kb = Qb + (size_t)BH_*S_*D_;
  unsigned short* Vb = Kb + (size_t)BH_*S_*D_;
  unsigned short* Vt = hsb;   // alias: hsb dead after qkv_gemm; sizes equal (M*HID == BH*S*D)

  hipLaunchKernelGGL(rope_tables, dim3(S_*32/256), dim3(256), 0, stream, cosT, sinT);
  hipLaunchKernelGGL(prep_hs, dim3(M_*HID_/(256*8)), dim3(256), 0, stream, hs, hsb);
  hipLaunchKernelGGL(prep_w, dim3(HID_/64, HID_/64, 3), dim3(256), 0, stream, Wq, Wk, Wv, WtAll);
  hipLaunchKernelGGL(qkv_gemm, dim3(HID_/128, M_/128, 3), dim3(256), 0, stream,
                     hsb, WtAll, bq, bk, bv, cosT, sinT, Qb, Kb, Vb);
  hipLaunchKernelGGL(transpose_v, dim3(S_/64, BH_), dim3(256), 0, stream, Vb, Vt);
  hipLaunchKernelGGL(attn, dim3(S_/128, BH_), dim3(256), 0, stream, Qb, Kb, Vt, mask, out);
}

// Round 3
// 267.306 us; speedup vs baseline: 1.8827x; 1.3326x over previous
//
#include <hip/hip_runtime.h>

#define B_   2
#define S_   2048
#define HID_ 1280
#define H_   20
#define D_   64
#define BH_  (B_*H_)   // 40
#define M_   (B_*S_)   // 4096

#define LOG2E 1.44269504f

typedef __bf16 bf16x8 __attribute__((ext_vector_type(8)));
typedef float  f32x4  __attribute__((ext_vector_type(4)));
typedef unsigned short u16x8 __attribute__((ext_vector_type(8)));
typedef unsigned short u16x4 __attribute__((ext_vector_type(4)));

__device__ __forceinline__ unsigned short bfbits(float x){
  __bf16 h = (__bf16)x;
  return *(unsigned short*)&h;
}

// async 16B global -> LDS (lane i lands at lds_base + i*16)
__device__ __forceinline__ void gl_lds16(const void* g, void* lds_base_uniform){
  __builtin_amdgcn_global_load_lds(
      (const __attribute__((address_space(1))) unsigned int*)g,
      (__attribute__((address_space(3))) unsigned int*)lds_base_uniform, 16, 0, 0);
}

// read a 16B fragment from an XOR-swizzled [rows][64-short] tile
__device__ __forceinline__ bf16x8 ldfrag(const unsigned short* T, int row, int chunk){
  return *(const bf16x8*)(T + row*64 + ((chunk ^ (row & 7)) * 8));
}

// ---------------- RoPE tables: cos/sin [S][32] ----------------
__global__ void rope_tables(float* __restrict__ cosT, float* __restrict__ sinT){
  int idx = blockIdx.x * 256 + threadIdx.x;
  int s = idx >> 5, j = idx & 31;
  float inv = 1.0f / powf(10000.0f, (float)(2*j) / 64.0f);
  float ang = (float)s * inv;
  float sn, cs; sincosf(ang, &sn, &cs);
  cosT[idx] = cs; sinT[idx] = sn;
}

// ---------------- hs fp32 -> bf16 ----------------
__global__ void prep_hs(const float* __restrict__ hs, unsigned short* __restrict__ hsb){
  size_t i = (size_t)(blockIdx.x * 256 + threadIdx.x) * 8;
  float4 a = *(const float4*)(hs + i), b = *(const float4*)(hs + i + 4);
  u16x8 o;
  o[0]=bfbits(a.x); o[1]=bfbits(a.y); o[2]=bfbits(a.z); o[3]=bfbits(a.w);
  o[4]=bfbits(b.x); o[5]=bfbits(b.y); o[6]=bfbits(b.z); o[7]=bfbits(b.w);
  *(u16x8*)(hsb + i) = o;
}

// ---------------- W fp32 [k][n] -> Wt bf16 [n][k] ----------------
__global__ __launch_bounds__(256) void prep_w(
    const float* __restrict__ Wq, const float* __restrict__ Wk, const float* __restrict__ Wv,
    unsigned short* __restrict__ WtAll){
  const int mode = blockIdx.z;
  const float* W = (mode==0) ? Wq : (mode==1 ? Wk : Wv);
  unsigned short* Wt = WtAll + (size_t)mode * HID_ * HID_;
  const int k0 = blockIdx.y * 64, n0 = blockIdx.x * 64;
  __shared__ __align__(16) unsigned short T[64][80];
  #pragma unroll
  for (int p = 0; p < 4; ++p){
    int idx = threadIdx.x + p*256;
    int row = idx >> 4, c4 = (idx & 15) * 4;
    float4 f = *(const float4*)(W + (size_t)(k0+row)*HID_ + n0 + c4);
    T[c4+0][row] = bfbits(f.x); T[c4+1][row] = bfbits(f.y);
    T[c4+2][row] = bfbits(f.z); T[c4+3][row] = bfbits(f.w);
  }
  __syncthreads();
  #pragma unroll
  for (int p = 0; p < 2; ++p){
    int idx = threadIdx.x + p*256;
    int n = idx >> 3, c8 = (idx & 7) * 8;
    u16x8 o = *(const u16x8*)&T[n][c8];
    *(u16x8*)(Wt + (size_t)(n0+n)*HID_ + k0 + c8) = o;
  }
}

// ---------------- QKV GEMM (bf16) + bias/scale/RoPE epilogue ----------------
__global__ __launch_bounds__(256) void qkv_gemm(
    const unsigned short* __restrict__ hsb, const unsigned short* __restrict__ WtAll,
    const float* __restrict__ bq, const float* __restrict__ bk, const float* __restrict__ bv,
    const float* __restrict__ cosT, const float* __restrict__ sinT,
    unsigned short* __restrict__ Qb, unsigned short* __restrict__ Kb,
    unsigned short* __restrict__ Vb)
{
  const int mode = blockIdx.z;
  const float* bias = (mode==0) ? bq : (mode==1 ? bk : bv);
  unsigned short* dst = (mode==0) ? Qb : (mode==1 ? Kb : Vb);
  const unsigned short* Wt = WtAll + (size_t)mode * HID_ * HID_;

  const int n0 = blockIdx.x * 128;
  const int m0 = blockIdx.y * 128;
  const int tid  = threadIdx.x;
  const int lane = tid & 63, wave = tid >> 6;
  const int c = lane & 15, quad = lane >> 4;
  const int wm = (wave & 1) * 64, wn = (wave >> 1) * 64;
  const int lrow = lane >> 3;
  const int lcol = ((lane & 7) ^ (lane >> 3)) * 8;   // XOR-swizzled source chunk

  __shared__ __align__(16) unsigned short As[128][64];  // swizzled [m][k]
  __shared__ __align__(16) unsigned short Bs[128][64];  // swizzled [n][k]

  f32x4 acc[4][4] = {};

  for (int k0 = 0; k0 < HID_; k0 += 64){
    __syncthreads();
    #pragma unroll
    for (int j = 0; j < 4; ++j){
      int rb = j*32 + wave*8;
      gl_lds16(hsb + (size_t)(m0 + rb + lrow)*HID_ + k0 + lcol, &As[rb][0]);
      gl_lds16(Wt  + (size_t)(n0 + rb + lrow)*HID_ + k0 + lcol, &Bs[rb][0]);
    }
    __syncthreads();

    #pragma unroll
    for (int kc = 0; kc < 2; ++kc){
      bf16x8 af[4], bfr[4];
      #pragma unroll
      for (int mi=0; mi<4; ++mi) af[mi]  = ldfrag(&As[0][0], wm + mi*16 + c, kc*4 + quad);
      #pragma unroll
      for (int ni=0; ni<4; ++ni) bfr[ni] = ldfrag(&Bs[0][0], wn + ni*16 + c, kc*4 + quad);
      #pragma unroll
      for (int mi=0; mi<4; ++mi)
        #pragma unroll
        for (int ni=0; ni<4; ++ni)
          acc[mi][ni] = __builtin_amdgcn_mfma_f32_16x16x32_bf16(af[mi], bfr[ni], acc[mi][ni], 0,0,0);
    }
  }

  // epilogue: wave's 64 cols == exactly one head
  const int h = (n0 + wn) >> 6;
  #pragma unroll
  for (int mi=0; mi<4; ++mi){
    #pragma unroll
    for (int i=0;i<4;++i){
      int row = m0 + wm + mi*16 + quad*4 + i;
      int b = row >> 11, s = row & (S_-1);
      size_t obase = ((size_t)(b*H_ + h)*S_ + s)*D_;
      if (mode < 2){
        #pragma unroll
        for (int ni=0; ni<2; ++ni){
          int d1 = ni*16 + c;             // 0..31
          float x1 = acc[mi][ni  ][i] + bias[n0 + wn + d1];
          float x2 = acc[mi][ni+2][i] + bias[n0 + wn + d1 + 32];
          if (mode == 0){ x1 *= 0.125f*LOG2E; x2 *= 0.125f*LOG2E; } // D^-0.5 and exp2-domain
          float cs = cosT[s*32 + d1], sn = sinT[s*32 + d1];
          dst[obase + d1]      = bfbits(x1*cs - x2*sn);
          dst[obase + d1 + 32] = bfbits(x2*cs + x1*sn);
        }
      } else {
        #pragma unroll
        for (int ni=0; ni<4; ++ni){
          int d = ni*16 + c;
          dst[obase + d] = bfbits(acc[mi][ni][i] + bias[n0 + wn + d]);
        }
      }
    }
  }
}

// ---------------- V [b,h,s,d] -> Vt [b,h,d,s] ----------------
__global__ __launch_bounds__(256) void transpose_v(
    const unsigned short* __restrict__ Vb, unsigned short* __restrict__ Vt){
  const int bh = blockIdx.y, s0 = blockIdx.x * 64;
  const size_t base = (size_t)bh * S_ * D_;
  __shared__ __align__(16) unsigned short T[64][80];
  #pragma unroll
  for (int p = 0; p < 2; ++p){
    int idx = threadIdx.x + p*256;
    int s = idx >> 3, c8 = (idx & 7) * 8;
    u16x8 v = *(const u16x8*)(Vb + base + (size_t)(s0+s)*D_ + c8);
    #pragma unroll
    for (int j=0;j<8;++j) T[c8+j][s] = v[j];
  }
  __syncthreads();
  #pragma unroll
  for (int p = 0; p < 2; ++p){
    int idx = threadIdx.x + p*256;
    int d = idx >> 3, s8 = (idx & 7) * 8;
    u16x8 o = *(const u16x8*)&T[d][s8];
    *(u16x8*)(Vt + base + (size_t)d*S_ + s0 + s8) = o;
  }
}

// ---------------- Flash attention, S^T formulation ----------------
// 128 q / block (wave owns 32), K/V tiles of 64 keys. Scores in exp2 domain.
__global__ __launch_bounds__(256) void attn(
    const unsigned short* __restrict__ Qb,
    const unsigned short* __restrict__ Kb,
    const unsigned short* __restrict__ Vt,
    const float* __restrict__ mask,
    float* __restrict__ out)
{
  const int tid  = threadIdx.x;
  const int lane = tid & 63, wave = tid >> 6;
  const int c = lane & 15, quad = lane >> 4;
  const int bh = blockIdx.y, b = bh / H_, h = bh % H_;
  const size_t base = (size_t)bh * (S_ * D_);
  const int q0 = blockIdx.x * 128;
  const int lrow = lane >> 3;
  const int lcol = ((lane & 7) ^ (lane >> 3)) * 8;   // XOR-swizzled source chunk

  __shared__ __align__(16) unsigned short Ks[64][64];    // swizzled [key][d]
  __shared__ __align__(16) unsigned short Vs[64][64];    // swizzled [d][key]
  __shared__ __align__(16) unsigned short Ps[4][32][72]; // per-wave P^T [q][key], padded
  __shared__ __align__(16) float mask_s[64];

  // Q as B-operand: lane c = q, k = kc*32 + quad*8 + j
  bf16x8 qf[2][2];
  #pragma unroll
  for (int qn=0; qn<2; ++qn)
    #pragma unroll
    for (int kc=0; kc<2; ++kc)
      qf[qn][kc] = *(const bf16x8*)(Qb + base + (size_t)(q0 + wave*32 + qn*16 + c)*D_ + kc*32 + quad*8);

  float m_i[2] = {-1e30f, -1e30f}, l_i[2] = {0.f, 0.f};
  f32x4 O[4][2] = {};   // [dt][qn], C-layout: col=q, row=d

  for (int kt0 = 0; kt0 < S_; kt0 += 64){
    __syncthreads();
    #pragma unroll
    for (int j = 0; j < 2; ++j){
      int rb = j*32 + wave*8;
      gl_lds16(Kb + base + (size_t)(kt0 + rb + lrow)*D_ + lcol, &Ks[rb][0]);
      gl_lds16(Vt + base + (size_t)(rb + lrow)*S_ + kt0 + lcol, &Vs[rb][0]);
    }
    if (tid < 64) mask_s[tid] = mask[b*S_ + kt0 + tid] * LOG2E;
    __syncthreads();

    // S^T tile: key = kt*16 + quad*4 + i, q = qn*16 + c   (already exp2-domain)
    f32x4 st[4][2];
    #pragma unroll
    for (int kt=0; kt<4; ++kt){
      bf16x8 ak0 = ldfrag(&Ks[0][0], kt*16 + c, quad);
      bf16x8 ak1 = ldfrag(&Ks[0][0], kt*16 + c, 4 + quad);
      float4 mk = *(const float4*)&mask_s[kt*16 + quad*4];
      #pragma unroll
      for (int qn=0; qn<2; ++qn){
        f32x4 z = {0.f,0.f,0.f,0.f};
        z = __builtin_amdgcn_mfma_f32_16x16x32_bf16(ak0, qf[qn][0], z, 0,0,0);
        z = __builtin_amdgcn_mfma_f32_16x16x32_bf16(ak1, qf[qn][1], z, 0,0,0);
        z[0] += mk.x; z[1] += mk.y; z[2] += mk.z; z[3] += mk.w;
        st[kt][qn] = z;
      }
    }

    // online softmax (exp2 domain); row q = this lane's column
    #pragma unroll
    for (int qn=0; qn<2; ++qn){
      float mx = -1e30f;
      #pragma unroll
      for (int kt=0; kt<4; ++kt)
        #pragma unroll
        for (int i=0;i<4;++i) mx = fmaxf(mx, st[kt][qn][i]);
      mx = fmaxf(mx, __shfl_xor(mx, 16, 64));
      mx = fmaxf(mx, __shfl_xor(mx, 32, 64));
      float mnew = fmaxf(m_i[qn], mx);
      float alpha = __builtin_amdgcn_exp2f(m_i[qn] - mnew);
      float sum = 0.f;
      #pragma unroll
      for (int kt=0; kt<4; ++kt){
        #pragma unroll
        for (int i=0;i<4;++i){
          float e = __builtin_amdgcn_exp2f(st[kt][qn][i] - mnew);
          st[kt][qn][i] = e; sum += e;
        }
      }
      sum += __shfl_xor(sum, 16, 64);
      sum += __shfl_xor(sum, 32, 64);
      l_i[qn] = l_i[qn]*alpha + sum;
      m_i[qn] = mnew;
      #pragma unroll
      for (int dt=0; dt<4; ++dt){
        O[dt][qn][0]*=alpha; O[dt][qn][1]*=alpha; O[dt][qn][2]*=alpha; O[dt][qn][3]*=alpha;
      }
      #pragma unroll
      for (int kt=0; kt<4; ++kt){
        u16x4 o; o[0]=bfbits(st[kt][qn][0]); o[1]=bfbits(st[kt][qn][1]);
                 o[2]=bfbits(st[kt][qn][2]); o[3]=bfbits(st[kt][qn][3]);
        *(u16x4*)&Ps[wave][qn*16 + c][kt*16 + quad*4] = o;
      }
    }

    // PV: O^T[d][q] += V^T[d][key] · P^T[key][q]
    bf16x8 pf[2][2];
    #pragma unroll
    for (int qn=0; qn<2; ++qn)
      #pragma unroll
      for (int k2=0; k2<2; ++k2)
        pf[qn][k2] = *(const bf16x8*)&Ps[wave][qn*16 + c][k2*32 + quad*8];
    #pragma unroll
    for (int dt=0; dt<4; ++dt){
      bf16x8 av0 = ldfrag(&Vs[0][0], dt*16 + c, quad);
      bf16x8 av1 = ldfrag(&Vs[0][0], dt*16 + c, 4 + quad);
      #pragma unroll
      for (int qn=0; qn<2; ++qn){
        O[dt][qn] = __builtin_amdgcn_mfma_f32_16x16x32_bf16(av0, pf[qn][0], O[dt][qn], 0,0,0);
        O[dt][qn] = __builtin_amdgcn_mfma_f32_16x16x32_bf16(av1, pf[qn][1], O[dt][qn], 0,0,0);
      }
    }
  }

  // epilogue: lane c = q; write float4 (4 consecutive d) per (dt,qn)
  #pragma unroll
  for (int qn=0; qn<2; ++qn){
    float inv = 1.0f / l_i[qn];
    int s = q0 + wave*32 + qn*16 + c;
    #pragma unroll
    for (int dt=0; dt<4; ++dt){
      float4 o;
      o.x = O[dt][qn][0]*inv; o.y = O[dt][qn][1]*inv;
      o.z = O[dt][qn][2]*inv; o.w = O[dt][qn][3]*inv;
      *(float4*)&out[((size_t)(b*S_ + s))*HID_ + h*D_ + dt*16 + quad*4] = o;
    }
  }
}

extern "C" void kernel_launch(void* const* d_in, const int* in_sizes, int n_in,
                              void* d_out, int out_size, void* d_ws, size_t ws_size,
                              hipStream_t stream){
  const float* hs   = (const float*)d_in[0];
  const float* mask = (const float*)d_in[1];
  const float* Wq   = (const float*)d_in[2];
  const float* bq   = (const float*)d_in[3];
  const float* Wk   = (const float*)d_in[4];
  const float* bk   = (const float*)d_in[5];
  const float* Wv   = (const float*)d_in[6];
  const float* bv   = (const float*)d_in[7];
  float* out = (float*)d_out;

  float* cosT = (float*)d_ws;
  float* sinT = cosT + S_*32;
  unsigned short* hsb   = (unsigned short*)(sinT + S_*32);
  unsigned short* WtAll = hsb + (size_t)M_*HID_;
  unsigned short* Qb = WtAll + (size_t)3*HID_*HID_;
  unsigned short* Kb = Qb + (size_t)BH_*S_*D_;
  unsigned short* Vb = Kb + (size_t)BH_*S_*D_;
  unsigned short* Vt = hsb;   // alias: hsb dead after qkv_gemm

  hipLaunchKernelGGL(rope_tables, dim3(S_*32/256), dim3(256), 0, stream, cosT, sinT);
  hipLaunchKernelGGL(prep_hs, dim3(M_*HID_/(256*8)), dim3(256), 0, stream, hs, hsb);
  hipLaunchKernelGGL(prep_w, dim3(HID_/64, HID_/64, 3), dim3(256), 0, stream, Wq, Wk, Wv, WtAll);
  hipLaunchKernelGGL(qkv_gemm, dim3(HID_/128, M_/128, 3), dim3(256), 0, stream,
                     hsb, WtAll, bq, bk, bv, cosT, sinT, Qb, Kb, Vb);
  hipLaunchKernelGGL(transpose_v, dim3(S_/64, BH_), dim3(256), 0, stream, Vb, Vt);
  hipLaunchKernelGGL(attn, dim3(S_/128, BH_), dim3(256), 0, stream, Qb, Kb, Vt, mask, out);
}